// Round 10
// baseline (793.496 us; speedup 1.0000x reference)
//
#include <hip/hip_runtime.h>
#include <hip/hip_bf16.h>
#include <stdint.h>

#define N_ROWS 8192
#define DIM    1024
#define TEMP_INV 10.0f
#define NCHUNK 16
#define CHUNK_COLS 512
#define BM 128
#define BN 128
#define BKB 128          // K-bytes per tile (fp8: 128 elems)
#define NEGINF (-__builtin_inff())
#define SCALE1 0x7F7F7F7F  // e8m0 scale bytes, all = 1.0

typedef __attribute__((ext_vector_type(4))) int i32x4;
typedef __attribute__((ext_vector_type(8))) int i32x8;
typedef __attribute__((ext_vector_type(4))) float f32x4;

__device__ __forceinline__ void gload_lds16(const void* g, void* l) {
  __builtin_amdgcn_global_load_lds(
      (const __attribute__((address_space(1))) unsigned int*)g,
      (__attribute__((address_space(3))) unsigned int*)l, 16, 0, 0);
}

// -------- Kernel 1: L2-normalize rows, convert to fp8 e4m3 --------
__global__ void norm_fp8_kernel(const float* __restrict__ ctx,
                                const float* __restrict__ gls,
                                unsigned char* __restrict__ Cn,
                                unsigned char* __restrict__ Gn) {
  int row = blockIdx.x;
  const float* src;
  unsigned char* dst;
  if (row < N_ROWS) { src = ctx + (size_t)row * DIM; dst = Cn + (size_t)row * DIM; }
  else { src = gls + (size_t)(row - N_ROWS) * DIM; dst = Gn + (size_t)(row - N_ROWS) * DIM; }
  int t = threadIdx.x;
  float4 v = ((const float4*)src)[t];
  float ss = v.x*v.x + v.y*v.y + v.z*v.z + v.w*v.w;
  #pragma unroll
  for (int m = 1; m < 64; m <<= 1) ss += __shfl_xor(ss, m);
  __shared__ float wss[4];
  if ((t & 63) == 0) wss[t >> 6] = ss;
  __syncthreads();
  float tot = wss[0] + wss[1] + wss[2] + wss[3];
  float inv = 1.0f / fmaxf(sqrtf(tot), 1e-12f);
  int pk = __builtin_amdgcn_cvt_pk_fp8_f32(v.x * inv, v.y * inv, 0, false);
  pk = __builtin_amdgcn_cvt_pk_fp8_f32(v.z * inv, v.w * inv, pk, true);
  *(unsigned int*)(dst + (size_t)t * 4) = (unsigned int)pk;
}

// -------- Kernel 2: fused MX-fp8 GEMM (16x16x128, unit scales) + exp + masked reductions --------
// Round-8 kernel (absmax 0.0) minus the sched_barrier that caused spill-thrash,
// plus waves_per_eu(2,2) so the allocator keeps the ~170 live regs without spilling.
__global__ __attribute__((amdgpu_flat_work_group_size(256, 256), amdgpu_waves_per_eu(2, 2)))
void gemm_reduce_kernel(const unsigned char* __restrict__ Cn,
                        const unsigned char* __restrict__ Gn,
                        const int* __restrict__ labels,
                        float* __restrict__ ws_sp,
                        float* __restrict__ ws_sa,
                        float* __restrict__ ws_mx) {
  __shared__ __align__(16) unsigned char As[BM * BKB];   // 16 KiB
  __shared__ __align__(16) unsigned char Bs[BN * BKB];   // 16 KiB
  __shared__ float red_sa[2][BM];
  __shared__ float red_sp[2][BM];
  __shared__ float red_mx[2][BM];

  const int tid = threadIdx.x;
  const int lane = tid & 63;
  const int wv = tid >> 6;
  const int wr = wv >> 1, wc = wv & 1;
  const int row0 = blockIdx.x * BM;
  const int chunk = blockIdx.y;
  const int g = lane >> 4;        // k-group 0..3
  const int fr = lane & 15;       // fragment row/col 0..15

  if (tid < BM) {
    red_sa[0][tid] = 0.f; red_sa[1][tid] = 0.f;
    red_sp[0][tid] = 0.f; red_sp[1][tid] = 0.f;
    red_mx[0][tid] = NEGINF; red_mx[1][tid] = NEGINF;
  }

  // staging: region r = wv*4+i covers rows r*8..r*8+7 (128 B each).
  // LDS written linearly; XOR swizzle pre-applied on the GLOBAL source
  // 16B-slot (slot ^= row&7)  [rule #21; verified rounds 2/7/9].
  const int srow = lane >> 3;                 // 0..7
  const int scol = (lane & 7) ^ srow;         // pre-swizzled 16B slot (8/row)

  // frag read slot byte-offsets (row&7 == fr&7): logical slots 2g, 2g+1
  const int sl0 = ((2 * g) ^ (fr & 7)) << 4;
  const int sl1 = ((2 * g + 1) ^ (fr & 7)) << 4;

  for (int ct = 0; ct < 4; ++ct) {
    const int col0 = chunk * CHUNK_COLS + ct * BN;
    f32x4 acc[4][4];
    #pragma unroll
    for (int m = 0; m < 4; ++m)
      #pragma unroll
      for (int n = 0; n < 4; ++n) {
        f32x4 z = {0.f, 0.f, 0.f, 0.f};
        acc[m][n] = z;
      }

    for (int kt = 0; kt < DIM / BKB; ++kt) {   // 8 iterations
      const int k0 = kt * BKB;
      #pragma unroll
      for (int i = 0; i < 4; ++i) {
        int r = wv * 4 + i;
        gload_lds16(Cn + (size_t)(row0 + r*8 + srow) * DIM + k0 + scol*16, &As[r * 1024]);
      }
      #pragma unroll
      for (int i = 0; i < 4; ++i) {
        int r = wv * 4 + i;
        gload_lds16(Gn + (size_t)(col0 + r*8 + srow) * DIM + k0 + scol*16, &Bs[r * 1024]);
      }
      __syncthreads();
      // B-fragments resident (32 VGPR)
      i32x8 bfr[4];
      #pragma unroll
      for (int n = 0; n < 4; ++n) {
        int rb = (wc*64 + n*16 + fr) * BKB;
        i32x4 lo = *(const i32x4*)&Bs[rb + sl0];
        i32x4 hi = *(const i32x4*)&Bs[rb + sl1];
        bfr[n] = __builtin_shufflevector(lo, hi, 0, 1, 2, 3, 4, 5, 6, 7);
      }
      // A-fragments per m (compiler-scheduled; no fences)
      #pragma unroll
      for (int m = 0; m < 4; ++m) {
        int rb = (wr*64 + m*16 + fr) * BKB;
        i32x4 lo = *(const i32x4*)&As[rb + sl0];
        i32x4 hi = *(const i32x4*)&As[rb + sl1];
        i32x8 af = __builtin_shufflevector(lo, hi, 0, 1, 2, 3, 4, 5, 6, 7);
        #pragma unroll
        for (int n = 0; n < 4; ++n)
          acc[m][n] = __builtin_amdgcn_mfma_scale_f32_16x16x128_f8f6f4(
              af, bfr[n], acc[m][n], 0, 0, 0, SCALE1, 0, SCALE1);
      }
      __syncthreads();
    }

    // per-ct epilogue: exp + masked accumulation into LDS (single writer/slot)
    int cl[4], cg[4];
    #pragma unroll
    for (int n = 0; n < 4; ++n) {
      cg[n] = col0 + wc*64 + n*16 + fr;
      cl[n] = labels[cg[n]];
    }
    #pragma unroll
    for (int m = 0; m < 4; ++m) {
      #pragma unroll
      for (int j = 0; j < 4; ++j) {
        const int rgi = row0 + wr*64 + m*16 + g*4 + j;
        const int rlab = labels[rgi];
        float va = 0.f, vp = 0.f, vm = NEGINF;
        #pragma unroll
        for (int n = 0; n < 4; ++n) {
          float s10 = acc[m][n][j] * TEMP_INV;
          float e = __expf(s10);
          bool offd = (rgi != cg[n]);
          float ea = offd ? e : 0.f;
          va += ea;
          vp += (rlab == cl[n]) ? ea : 0.f;
          vm = offd ? fmaxf(vm, s10) : vm;
        }
        #pragma unroll
        for (int mk = 1; mk < 16; mk <<= 1) {
          va += __shfl_xor(va, mk);
          vp += __shfl_xor(vp, mk);
          vm = fmaxf(vm, __shfl_xor(vm, mk));
        }
        if (fr == 0) {
          int rloc = wr*64 + m*16 + g*4 + j;
          red_sa[wc][rloc] += va;
          red_sp[wc][rloc] += vp;
          red_mx[wc][rloc] = fmaxf(red_mx[wc][rloc], vm);
        }
      }
    }
  }

  __syncthreads();
  if (tid < BM) {
    size_t o = (size_t)chunk * N_ROWS + row0 + tid;
    ws_sa[o] = red_sa[0][tid] + red_sa[1][tid];
    ws_sp[o] = red_sp[0][tid] + red_sp[1][tid];
    ws_mx[o] = fmaxf(red_mx[0][tid], red_mx[1][tid]);
  }
}

// -------- Kernel 3: combine chunk partials -> per-row loss --------
__global__ void finalize_rows_kernel(const float* __restrict__ ws_sp,
                                     const float* __restrict__ ws_sa,
                                     const float* __restrict__ ws_mx,
                                     float* __restrict__ ws_loss) {
  int r = blockIdx.x * blockDim.x + threadIdx.x;
  float sp = 0.f, sa = 0.f, mx = NEGINF;
  #pragma unroll
  for (int c = 0; c < NCHUNK; ++c) {
    sp += ws_sp[(size_t)c * N_ROWS + r];
    sa += ws_sa[(size_t)c * N_ROWS + r];
    mx = fmaxf(mx, ws_mx[(size_t)c * N_ROWS + r]);
  }
  float frac = (sp + 1e-8f) / (sa + 1e-8f);
  frac = fminf(fmaxf(frac, 1e-8f), 1.0f);
  float loss = -logf(frac);
  if (sp == 0.0f) loss = -mx;   // no-positives fallback (every exp term > 0)
  ws_loss[r] = loss;
}

// -------- Kernel 4: deterministic mean --------
__global__ void mean_kernel(const float* __restrict__ ws_loss, float* __restrict__ out) {
  int t = threadIdx.x;
  float s = 0.f;
  for (int i = t; i < N_ROWS; i += 256) s += ws_loss[i];
  #pragma unroll
  for (int m = 1; m < 64; m <<= 1) s += __shfl_xor(s, m);
  __shared__ float wsum[4];
  if ((t & 63) == 0) wsum[t >> 6] = s;
  __syncthreads();
  if (t == 0) out[0] = (wsum[0] + wsum[1] + wsum[2] + wsum[3]) * (1.0f / N_ROWS);
}

extern "C" void kernel_launch(void* const* d_in, const int* in_sizes, int n_in,
                              void* d_out, int out_size, void* d_ws, size_t ws_size,
                              hipStream_t stream) {
  const float* ctx = (const float*)d_in[0];
  const float* gls = (const float*)d_in[1];
  const int* labels = (const int*)d_in[2];
  float* out = (float*)d_out;

  char* ws = (char*)d_ws;
  unsigned char* Cn = (unsigned char*)ws;                                 // 8 MiB
  unsigned char* Gn = (unsigned char*)(ws + (size_t)N_ROWS * DIM);        // 8 MiB
  float* ws_sp = (float*)(ws + (size_t)2 * N_ROWS * DIM);
  float* ws_sa = ws_sp + (size_t)NCHUNK * N_ROWS;
  float* ws_mx = ws_sa + (size_t)NCHUNK * N_ROWS;
  float* ws_loss = ws_mx + (size_t)NCHUNK * N_ROWS;

  hipLaunchKernelGGL(norm_fp8_kernel, dim3(2 * N_ROWS), dim3(256), 0, stream,
                     ctx, gls, Cn, Gn);
  hipLaunchKernelGGL(gemm_reduce_kernel, dim3(N_ROWS / BM, NCHUNK), dim3(256), 0, stream,
                     Cn, Gn, labels, ws_sp, ws_sa, ws_mx);
  hipLaunchKernelGGL(finalize_rows_kernel, dim3(N_ROWS / 256), dim3(256), 0, stream,
                     ws_sp, ws_sa, ws_mx, ws_loss);
  hipLaunchKernelGGL(mean_kernel, dim3(1), dim3(256), 0, stream, ws_loss, out);
}

// Round 11
// 154.841 us; speedup vs baseline: 5.1246x; 5.1246x over previous
//
#include <hip/hip_runtime.h>
#include <hip/hip_bf16.h>
#include <stdint.h>

#define N_ROWS 8192
#define DIM    1024            // elements per row; fp8 => also bytes per row
#define TEMP_INV 10.0f
#define NCHUNK 16
#define CHUNK_COLS 512
#define BM 128
#define BN 128
#define BKB 128                // K-bytes per tile (fp8: 128 elems)
#define NEGINF (-__builtin_inff())

typedef __attribute__((ext_vector_type(2))) long i64x2;
typedef __attribute__((ext_vector_type(4))) float f32x4;

__device__ __forceinline__ void gload_lds16(const void* g, void* l) {
  __builtin_amdgcn_global_load_lds(
      (const __attribute__((address_space(1))) unsigned int*)g,
      (__attribute__((address_space(3))) unsigned int*)l, 16, 0, 0);
}

// -------- Kernel 1: L2-normalize rows, convert to fp8 e4m3 --------
__global__ void norm_fp8_kernel(const float* __restrict__ ctx,
                                const float* __restrict__ gls,
                                unsigned char* __restrict__ Cn,
                                unsigned char* __restrict__ Gn) {
  int row = blockIdx.x;
  const float* src;
  unsigned char* dst;
  if (row < N_ROWS) { src = ctx + (size_t)row * DIM; dst = Cn + (size_t)row * DIM; }
  else { src = gls + (size_t)(row - N_ROWS) * DIM; dst = Gn + (size_t)(row - N_ROWS) * DIM; }
  int t = threadIdx.x;
  float4 v = ((const float4*)src)[t];
  float ss = v.x*v.x + v.y*v.y + v.z*v.z + v.w*v.w;
  #pragma unroll
  for (int m = 1; m < 64; m <<= 1) ss += __shfl_xor(ss, m);
  __shared__ float wss[4];
  if ((t & 63) == 0) wss[t >> 6] = ss;
  __syncthreads();
  float tot = wss[0] + wss[1] + wss[2] + wss[3];
  float inv = 1.0f / fmaxf(sqrtf(tot), 1e-12f);
  int pk = __builtin_amdgcn_cvt_pk_fp8_f32(v.x * inv, v.y * inv, 0, false);
  pk = __builtin_amdgcn_cvt_pk_fp8_f32(v.z * inv, v.w * inv, pk, true);
  *(unsigned int*)(dst + (size_t)t * 4) = (unsigned int)pk;
}

// -------- Kernel 2: fused fp8 GEMM (16x16x32_fp8_fp8, BK=128B) + exp + masked reductions --------
// Round-9 kernel (125us, MfmaUtil 45.5%, 0 conflicts) with the per-ct LDS
// epilogue from round 8 (absmax 0.0) replacing the 64 persistent VGPRs of
// s_all/s_pos/s_max/rl -> spill-free at the 128-VGPR / 2-wave budget.
__global__ __launch_bounds__(256, 2)
void gemm_reduce_kernel(const unsigned char* __restrict__ Cn,
                        const unsigned char* __restrict__ Gn,
                        const int* __restrict__ labels,
                        float* __restrict__ ws_sp,
                        float* __restrict__ ws_sa,
                        float* __restrict__ ws_mx) {
  __shared__ __align__(16) unsigned char As[BM * BKB];   // 16 KiB
  __shared__ __align__(16) unsigned char Bs[BN * BKB];   // 16 KiB
  __shared__ float red_sa[2][BM];
  __shared__ float red_sp[2][BM];
  __shared__ float red_mx[2][BM];

  const int tid = threadIdx.x;
  const int lane = tid & 63;
  const int wv = tid >> 6;
  const int wr = wv >> 1, wc = wv & 1;
  const int row0 = blockIdx.x * BM;
  const int chunk = blockIdx.y;
  const int g = lane >> 4;        // k-group 0..3
  const int fr = lane & 15;       // fragment row/col 0..15
  const int fr7 = fr & 7;

  if (tid < BM) {
    red_sa[0][tid] = 0.f; red_sa[1][tid] = 0.f;
    red_sp[0][tid] = 0.f; red_sp[1][tid] = 0.f;
    red_mx[0][tid] = NEGINF; red_mx[1][tid] = NEGINF;
  }

  // staging: region r = wv*4+i covers rows r*8..r*8+7 (128 B each).
  // LDS written linearly (base + lane*16B); XOR swizzle pre-applied on the
  // GLOBAL source 16B-slot (slot ^= row&7)  [rule #21; verified rounds 2/9].
  const int srow = lane >> 3;                 // 0..7
  const int scol = (lane & 7) ^ srow;         // pre-swizzled 16B slot (8/row)

  // frag read slot byte-offsets (row&7 == fr&7): slots g and 4+g
  const int sl0 = ((g) ^ fr7) << 4;
  const int sl1 = ((4 + g) ^ fr7) << 4;

  for (int ct = 0; ct < 4; ++ct) {
    const int col0 = chunk * CHUNK_COLS + ct * BN;
    f32x4 acc[4][4];
    #pragma unroll
    for (int m = 0; m < 4; ++m)
      #pragma unroll
      for (int n = 0; n < 4; ++n) {
        f32x4 z = {0.f, 0.f, 0.f, 0.f};
        acc[m][n] = z;
      }

    for (int kt = 0; kt < DIM / BKB; ++kt) {   // 8 iterations
      const int k0 = kt * BKB;
      #pragma unroll
      for (int i = 0; i < 4; ++i) {
        int r = wv * 4 + i;
        gload_lds16(Cn + (size_t)(row0 + r*8 + srow) * DIM + k0 + scol*16, &As[r * 1024]);
      }
      #pragma unroll
      for (int i = 0; i < 4; ++i) {
        int r = wv * 4 + i;
        gload_lds16(Gn + (size_t)(col0 + r*8 + srow) * DIM + k0 + scol*16, &Bs[r * 1024]);
      }
      __syncthreads();
      // half-phase 0: slot g  (32 frag VGPRs live), 32 MFMAs
      {
        i64x2 af[4], bfr[4];
        #pragma unroll
        for (int m = 0; m < 4; ++m)
          af[m] = *(const i64x2*)&As[(wr*64 + m*16 + fr) * BKB + sl0];
        #pragma unroll
        for (int n = 0; n < 4; ++n)
          bfr[n] = *(const i64x2*)&Bs[(wc*64 + n*16 + fr) * BKB + sl0];
        #pragma unroll
        for (int m = 0; m < 4; ++m)
          #pragma unroll
          for (int n = 0; n < 4; ++n) {
            acc[m][n] = __builtin_amdgcn_mfma_f32_16x16x32_fp8_fp8(
                af[m][0], bfr[n][0], acc[m][n], 0, 0, 0);
            acc[m][n] = __builtin_amdgcn_mfma_f32_16x16x32_fp8_fp8(
                af[m][1], bfr[n][1], acc[m][n], 0, 0, 0);
          }
      }
      // half-phase 1: slot 4+g, 32 MFMAs
      {
        i64x2 af[4], bfr[4];
        #pragma unroll
        for (int m = 0; m < 4; ++m)
          af[m] = *(const i64x2*)&As[(wr*64 + m*16 + fr) * BKB + sl1];
        #pragma unroll
        for (int n = 0; n < 4; ++n)
          bfr[n] = *(const i64x2*)&Bs[(wc*64 + n*16 + fr) * BKB + sl1];
        #pragma unroll
        for (int m = 0; m < 4; ++m)
          #pragma unroll
          for (int n = 0; n < 4; ++n) {
            acc[m][n] = __builtin_amdgcn_mfma_f32_16x16x32_fp8_fp8(
                af[m][0], bfr[n][0], acc[m][n], 0, 0, 0);
            acc[m][n] = __builtin_amdgcn_mfma_f32_16x16x32_fp8_fp8(
                af[m][1], bfr[n][1], acc[m][n], 0, 0, 0);
          }
      }
      __syncthreads();
    }

    // per-ct epilogue: exp + masked accumulation into LDS (single writer/slot)
    int cl[4], cg[4];
    #pragma unroll
    for (int n = 0; n < 4; ++n) {
      cg[n] = col0 + wc*64 + n*16 + fr;
      cl[n] = labels[cg[n]];
    }
    #pragma unroll
    for (int m = 0; m < 4; ++m) {
      #pragma unroll
      for (int j = 0; j < 4; ++j) {
        const int rgi = row0 + wr*64 + m*16 + g*4 + j;
        const int rlab = labels[rgi];
        float va = 0.f, vp = 0.f, vm = NEGINF;
        #pragma unroll
        for (int n = 0; n < 4; ++n) {
          float s10 = acc[m][n][j] * TEMP_INV;
          float e = __expf(s10);
          bool offd = (rgi != cg[n]);
          float ea = offd ? e : 0.f;
          va += ea;
          vp += (rlab == cl[n]) ? ea : 0.f;
          vm = offd ? fmaxf(vm, s10) : vm;
        }
        #pragma unroll
        for (int mk = 1; mk < 16; mk <<= 1) {
          va += __shfl_xor(va, mk);
          vp += __shfl_xor(vp, mk);
          vm = fmaxf(vm, __shfl_xor(vm, mk));
        }
        if (fr == 0) {
          int rloc = wr*64 + m*16 + g*4 + j;
          red_sa[wc][rloc] += va;
          red_sp[wc][rloc] += vp;
          red_mx[wc][rloc] = fmaxf(red_mx[wc][rloc], vm);
        }
      }
    }
  }

  __syncthreads();
  if (tid < BM) {
    size_t o = (size_t)chunk * N_ROWS + row0 + tid;
    ws_sa[o] = red_sa[0][tid] + red_sa[1][tid];
    ws_sp[o] = red_sp[0][tid] + red_sp[1][tid];
    ws_mx[o] = fmaxf(red_mx[0][tid], red_mx[1][tid]);
  }
}

// -------- Kernel 3: combine chunk partials -> per-row loss --------
__global__ void finalize_rows_kernel(const float* __restrict__ ws_sp,
                                     const float* __restrict__ ws_sa,
                                     const float* __restrict__ ws_mx,
                                     float* __restrict__ ws_loss) {
  int r = blockIdx.x * blockDim.x + threadIdx.x;
  float sp = 0.f, sa = 0.f, mx = NEGINF;
  #pragma unroll
  for (int c = 0; c < NCHUNK; ++c) {
    sp += ws_sp[(size_t)c * N_ROWS + r];
    sa += ws_sa[(size_t)c * N_ROWS + r];
    mx = fmaxf(mx, ws_mx[(size_t)c * N_ROWS + r]);
  }
  float frac = (sp + 1e-8f) / (sa + 1e-8f);
  frac = fminf(fmaxf(frac, 1e-8f), 1.0f);
  float loss = -logf(frac);
  if (sp == 0.0f) loss = -mx;   // no-positives fallback (every exp term > 0)
  ws_loss[r] = loss;
}

// -------- Kernel 4: deterministic mean --------
__global__ void mean_kernel(const float* __restrict__ ws_loss, float* __restrict__ out) {
  int t = threadIdx.x;
  float s = 0.f;
  for (int i = t; i < N_ROWS; i += 256) s += ws_loss[i];
  #pragma unroll
  for (int m = 1; m < 64; m <<= 1) s += __shfl_xor(s, m);
  __shared__ float wsum[4];
  if ((t & 63) == 0) wsum[t >> 6] = s;
  __syncthreads();
  if (t == 0) out[0] = (wsum[0] + wsum[1] + wsum[2] + wsum[3]) * (1.0f / N_ROWS);
}

extern "C" void kernel_launch(void* const* d_in, const int* in_sizes, int n_in,
                              void* d_out, int out_size, void* d_ws, size_t ws_size,
                              hipStream_t stream) {
  const float* ctx = (const float*)d_in[0];
  const float* gls = (const float*)d_in[1];
  const int* labels = (const int*)d_in[2];
  float* out = (float*)d_out;

  char* ws = (char*)d_ws;
  unsigned char* Cn = (unsigned char*)ws;                                 // 8 MiB
  unsigned char* Gn = (unsigned char*)(ws + (size_t)N_ROWS * DIM);        // 8 MiB
  float* ws_sp = (float*)(ws + (size_t)2 * N_ROWS * DIM);
  float* ws_sa = ws_sp + (size_t)NCHUNK * N_ROWS;
  float* ws_mx = ws_sa + (size_t)NCHUNK * N_ROWS;
  float* ws_loss = ws_mx + (size_t)NCHUNK * N_ROWS;

  hipLaunchKernelGGL(norm_fp8_kernel, dim3(2 * N_ROWS), dim3(256), 0, stream,
                     ctx, gls, Cn, Gn);
  hipLaunchKernelGGL(gemm_reduce_kernel, dim3(N_ROWS / BM, NCHUNK), dim3(256), 0, stream,
                     Cn, Gn, labels, ws_sp, ws_sa, ws_mx);
  hipLaunchKernelGGL(finalize_rows_kernel, dim3(N_ROWS / 256), dim3(256), 0, stream,
                     ws_sp, ws_sa, ws_mx, ws_loss);
  hipLaunchKernelGGL(mean_kernel, dim3(1), dim3(256), 0, stream, ws_loss, out);
}

// Round 12
// 147.283 us; speedup vs baseline: 5.3875x; 1.0513x over previous
//
#include <hip/hip_runtime.h>
#include <hip/hip_bf16.h>
#include <stdint.h>

#define N_ROWS 8192
#define DIM    1024            // elements per row; fp8 => also bytes per row
#define TEMP_INV 10.0f
#define NCHUNK 16
#define CHUNK_COLS 512
#define BM 128
#define BN 128
#define BKB 128                // K-bytes per tile (fp8: 128 elems)
#define NEGINF (-__builtin_inff())

typedef __attribute__((ext_vector_type(2))) long i64x2;
typedef __attribute__((ext_vector_type(4))) float f32x4;

__device__ __forceinline__ void gload_lds16(const void* g, void* l) {
  __builtin_amdgcn_global_load_lds(
      (const __attribute__((address_space(1))) unsigned int*)g,
      (__attribute__((address_space(3))) unsigned int*)l, 16, 0, 0);
}

// -------- Kernel 1: L2-normalize rows, convert to fp8 e4m3 --------
__global__ void norm_fp8_kernel(const float* __restrict__ ctx,
                                const float* __restrict__ gls,
                                unsigned char* __restrict__ Cn,
                                unsigned char* __restrict__ Gn) {
  int row = blockIdx.x;
  const float* src;
  unsigned char* dst;
  if (row < N_ROWS) { src = ctx + (size_t)row * DIM; dst = Cn + (size_t)row * DIM; }
  else { src = gls + (size_t)(row - N_ROWS) * DIM; dst = Gn + (size_t)(row - N_ROWS) * DIM; }
  int t = threadIdx.x;
  float4 v = ((const float4*)src)[t];
  float ss = v.x*v.x + v.y*v.y + v.z*v.z + v.w*v.w;
  #pragma unroll
  for (int m = 1; m < 64; m <<= 1) ss += __shfl_xor(ss, m);
  __shared__ float wss[4];
  if ((t & 63) == 0) wss[t >> 6] = ss;
  __syncthreads();
  float tot = wss[0] + wss[1] + wss[2] + wss[3];
  float inv = 1.0f / fmaxf(sqrtf(tot), 1e-12f);
  int pk = __builtin_amdgcn_cvt_pk_fp8_f32(v.x * inv, v.y * inv, 0, false);
  pk = __builtin_amdgcn_cvt_pk_fp8_f32(v.z * inv, v.w * inv, pk, true);
  *(unsigned int*)(dst + (size_t)t * 4) = (unsigned int)pk;
}

// -------- Kernel 2: fused fp8 GEMM (16x16x32_fp8_fp8, BK=128B) + exp + masked reductions --------
// Round-9 winner (125us, MfmaUtil 45.5%, 0 conflicts) with reduced persistent
// registers: row labels from LDS (drops rl[16]); max tracked on ea (=exp val),
// dropping a cndmask and letting the compiler fold the exp prescale.
__global__ __launch_bounds__(256, 2)
void gemm_reduce_kernel(const unsigned char* __restrict__ Cn,
                        const unsigned char* __restrict__ Gn,
                        const int* __restrict__ labels,
                        float* __restrict__ ws_sp,
                        float* __restrict__ ws_sa,
                        float* __restrict__ ws_mx) {
  __shared__ __align__(16) unsigned char As[BM * BKB];   // 16 KiB
  __shared__ __align__(16) unsigned char Bs[BN * BKB];   // 16 KiB
  __shared__ float red_sa[2][BM];
  __shared__ float red_sp[2][BM];
  __shared__ float red_mx[2][BM];
  __shared__ int lab_lds[BM];

  const int tid = threadIdx.x;
  const int lane = tid & 63;
  const int wv = tid >> 6;
  const int wr = wv >> 1, wc = wv & 1;
  const int row0 = blockIdx.x * BM;
  const int chunk = blockIdx.y;
  const int g = lane >> 4;        // k-group 0..3
  const int fr = lane & 15;       // fragment row/col 0..15
  const int fr7 = fr & 7;

  if (tid < BM) lab_lds[tid] = labels[row0 + tid];

  // staging: region r = wv*4+i covers rows r*8..r*8+7 (128 B each).
  // LDS written linearly (base + lane*16B); XOR swizzle pre-applied on the
  // GLOBAL source 16B-slot (slot ^= row&7)  [rule #21; verified rounds 2/9].
  const int srow = lane >> 3;                 // 0..7
  const int scol = (lane & 7) ^ srow;         // pre-swizzled 16B slot (8/row)

  // frag read slot byte-offsets (row&7 == fr&7): slots g and 4+g
  const int sl0 = ((g) ^ fr7) << 4;
  const int sl1 = ((4 + g) ^ fr7) << 4;

  float s_all[16], s_pos[16], s_max[16];
  #pragma unroll
  for (int t = 0; t < 16; ++t) { s_all[t] = 0.f; s_pos[t] = 0.f; s_max[t] = 0.f; }

  for (int ct = 0; ct < 4; ++ct) {
    const int col0 = chunk * CHUNK_COLS + ct * BN;
    f32x4 acc[4][4];
    #pragma unroll
    for (int m = 0; m < 4; ++m)
      #pragma unroll
      for (int n = 0; n < 4; ++n) {
        f32x4 z = {0.f, 0.f, 0.f, 0.f};
        acc[m][n] = z;
      }

    for (int kt = 0; kt < DIM / BKB; ++kt) {   // 8 iterations
      const int k0 = kt * BKB;
      #pragma unroll
      for (int i = 0; i < 4; ++i) {
        int r = wv * 4 + i;
        gload_lds16(Cn + (size_t)(row0 + r*8 + srow) * DIM + k0 + scol*16, &As[r * 1024]);
      }
      #pragma unroll
      for (int i = 0; i < 4; ++i) {
        int r = wv * 4 + i;
        gload_lds16(Gn + (size_t)(col0 + r*8 + srow) * DIM + k0 + scol*16, &Bs[r * 1024]);
      }
      __syncthreads();
      // half-phase 0: slot g  (32 frag VGPRs live), 32 MFMAs
      {
        i64x2 af[4], bfr[4];
        #pragma unroll
        for (int m = 0; m < 4; ++m)
          af[m] = *(const i64x2*)&As[(wr*64 + m*16 + fr) * BKB + sl0];
        #pragma unroll
        for (int n = 0; n < 4; ++n)
          bfr[n] = *(const i64x2*)&Bs[(wc*64 + n*16 + fr) * BKB + sl0];
        #pragma unroll
        for (int m = 0; m < 4; ++m)
          #pragma unroll
          for (int n = 0; n < 4; ++n) {
            acc[m][n] = __builtin_amdgcn_mfma_f32_16x16x32_fp8_fp8(
                af[m][0], bfr[n][0], acc[m][n], 0, 0, 0);
            acc[m][n] = __builtin_amdgcn_mfma_f32_16x16x32_fp8_fp8(
                af[m][1], bfr[n][1], acc[m][n], 0, 0, 0);
          }
      }
      // half-phase 1: slot 4+g, 32 MFMAs
      {
        i64x2 af[4], bfr[4];
        #pragma unroll
        for (int m = 0; m < 4; ++m)
          af[m] = *(const i64x2*)&As[(wr*64 + m*16 + fr) * BKB + sl1];
        #pragma unroll
        for (int n = 0; n < 4; ++n)
          bfr[n] = *(const i64x2*)&Bs[(wc*64 + n*16 + fr) * BKB + sl1];
        #pragma unroll
        for (int m = 0; m < 4; ++m)
          #pragma unroll
          for (int n = 0; n < 4; ++n) {
            acc[m][n] = __builtin_amdgcn_mfma_f32_16x16x32_fp8_fp8(
                af[m][0], bfr[n][0], acc[m][n], 0, 0, 0);
            acc[m][n] = __builtin_amdgcn_mfma_f32_16x16x32_fp8_fp8(
                af[m][1], bfr[n][1], acc[m][n], 0, 0, 0);
          }
      }
      __syncthreads();
    }

    // epilogue: exp + masked accumulation (row labels from LDS; max on ea)
    int cl[4], cg[4];
    #pragma unroll
    for (int n = 0; n < 4; ++n) {
      cg[n] = col0 + wc*64 + n*16 + fr;
      cl[n] = labels[cg[n]];
    }
    #pragma unroll
    for (int m = 0; m < 4; ++m) {
      #pragma unroll
      for (int j = 0; j < 4; ++j) {
        const int t = m*4 + j;
        const int rloc = wr*64 + m*16 + g*4 + j;
        const int rgi = row0 + rloc;
        const int rlab = lab_lds[rloc];
        #pragma unroll
        for (int n = 0; n < 4; ++n) {
          float e = __expf(acc[m][n][j] * TEMP_INV);   // s10 only feeds exp -> 1 mul
          bool offd = (rgi != cg[n]);
          float ea = offd ? e : 0.f;
          s_all[t] += ea;
          if (rlab == cl[n]) s_pos[t] += ea;
          s_max[t] = fmaxf(s_max[t], ea);              // max_ea; ln() in finalize
        }
      }
    }
  }

  // reduce across the 16 lanes sharing each row (same g-group)
  #pragma unroll
  for (int t = 0; t < 16; ++t) {
    float va = s_all[t], vp = s_pos[t], vm = s_max[t];
    #pragma unroll
    for (int m = 1; m < 16; m <<= 1) {
      va += __shfl_xor(va, m);
      vp += __shfl_xor(vp, m);
      vm = fmaxf(vm, __shfl_xor(vm, m));
    }
    if (fr == 0) {
      int rloc = wr*64 + (t >> 2)*16 + g*4 + (t & 3);
      red_sa[wc][rloc] = va;
      red_sp[wc][rloc] = vp;
      red_mx[wc][rloc] = vm;
    }
  }
  __syncthreads();
  if (tid < BM) {
    size_t o = (size_t)chunk * N_ROWS + row0 + tid;
    ws_sa[o] = red_sa[0][tid] + red_sa[1][tid];
    ws_sp[o] = red_sp[0][tid] + red_sp[1][tid];
    ws_mx[o] = fmaxf(red_mx[0][tid], red_mx[1][tid]);
  }
}

// -------- Kernel 3: combine chunk partials -> per-row loss -> block partial sums --------
__global__ void finalize_rows_kernel(const float* __restrict__ ws_sp,
                                     const float* __restrict__ ws_sa,
                                     const float* __restrict__ ws_mx,
                                     float* __restrict__ ws_part) {
  int r = blockIdx.x * blockDim.x + threadIdx.x;
  float sp = 0.f, sa = 0.f, mx = 0.f;
  #pragma unroll
  for (int c = 0; c < NCHUNK; ++c) {
    sp += ws_sp[(size_t)c * N_ROWS + r];
    sa += ws_sa[(size_t)c * N_ROWS + r];
    mx = fmaxf(mx, ws_mx[(size_t)c * N_ROWS + r]);
  }
  float frac = (sp + 1e-8f) / (sa + 1e-8f);
  frac = fminf(fmaxf(frac, 1e-8f), 1.0f);
  float loss = -logf(frac);
  if (sp == 0.0f) loss = -logf(mx);   // no-positives: -max_neg = -ln(max ea)
  // deterministic block reduction
  int t = threadIdx.x;
  #pragma unroll
  for (int m = 1; m < 64; m <<= 1) loss += __shfl_xor(loss, m);
  __shared__ float wsum[4];
  if ((t & 63) == 0) wsum[t >> 6] = loss;
  __syncthreads();
  if (t == 0) ws_part[blockIdx.x] = (wsum[0] + wsum[1]) + (wsum[2] + wsum[3]);
}

// -------- Kernel 4: deterministic mean over 32 block partials --------
__global__ void mean_kernel(const float* __restrict__ ws_part, float* __restrict__ out) {
  int t = threadIdx.x;                       // 64 threads
  float s = (t < N_ROWS / 256) ? ws_part[t] : 0.f;
  #pragma unroll
  for (int m = 1; m < 64; m <<= 1) s += __shfl_xor(s, m);
  if (t == 0) out[0] = s * (1.0f / N_ROWS);
}

extern "C" void kernel_launch(void* const* d_in, const int* in_sizes, int n_in,
                              void* d_out, int out_size, void* d_ws, size_t ws_size,
                              hipStream_t stream) {
  const float* ctx = (const float*)d_in[0];
  const float* gls = (const float*)d_in[1];
  const int* labels = (const int*)d_in[2];
  float* out = (float*)d_out;

  char* ws = (char*)d_ws;
  unsigned char* Cn = (unsigned char*)ws;                                 // 8 MiB
  unsigned char* Gn = (unsigned char*)(ws + (size_t)N_ROWS * DIM);        // 8 MiB
  float* ws_sp = (float*)(ws + (size_t)2 * N_ROWS * DIM);
  float* ws_sa = ws_sp + (size_t)NCHUNK * N_ROWS;
  float* ws_mx = ws_sa + (size_t)NCHUNK * N_ROWS;
  float* ws_part = ws_mx + (size_t)NCHUNK * N_ROWS;

  hipLaunchKernelGGL(norm_fp8_kernel, dim3(2 * N_ROWS), dim3(256), 0, stream,
                     ctx, gls, Cn, Gn);
  hipLaunchKernelGGL(gemm_reduce_kernel, dim3(N_ROWS / BM, NCHUNK), dim3(256), 0, stream,
                     Cn, Gn, labels, ws_sp, ws_sa, ws_mx);
  hipLaunchKernelGGL(finalize_rows_kernel, dim3(N_ROWS / 256), dim3(256), 0, stream,
                     ws_sp, ws_sa, ws_mx, ws_part);
  hipLaunchKernelGGL(mean_kernel, dim3(1), dim3(64), 0, stream, ws_part, out);
}

// Round 13
// 143.478 us; speedup vs baseline: 5.5304x; 1.0265x over previous
//
#include <hip/hip_runtime.h>
#include <hip/hip_bf16.h>
#include <stdint.h>

#define N_ROWS 8192
#define DIM    1024            // elements per row; fp8 => also bytes per row
#define TEMP_INV 10.0f
#define NCHUNK 64
#define BM 128
#define BN 128
#define BKB 128                // K-bytes per tile (fp8: 128 elems)
#define NEGINF (-__builtin_inff())

typedef __attribute__((ext_vector_type(2))) long i64x2;
typedef __attribute__((ext_vector_type(4))) float f32x4;

__device__ __forceinline__ void gload_lds16(const void* g, void* l) {
  __builtin_amdgcn_global_load_lds(
      (const __attribute__((address_space(1))) unsigned int*)g,
      (__attribute__((address_space(3))) unsigned int*)l, 16, 0, 0);
}

// -------- Kernel 1: L2-normalize rows, convert to fp8 e4m3 --------
__global__ void norm_fp8_kernel(const float* __restrict__ ctx,
                                const float* __restrict__ gls,
                                unsigned char* __restrict__ Cn,
                                unsigned char* __restrict__ Gn) {
  int row = blockIdx.x;
  const float* src;
  unsigned char* dst;
  if (row < N_ROWS) { src = ctx + (size_t)row * DIM; dst = Cn + (size_t)row * DIM; }
  else { src = gls + (size_t)(row - N_ROWS) * DIM; dst = Gn + (size_t)(row - N_ROWS) * DIM; }
  int t = threadIdx.x;
  float4 v = ((const float4*)src)[t];
  float ss = v.x*v.x + v.y*v.y + v.z*v.z + v.w*v.w;
  #pragma unroll
  for (int m = 1; m < 64; m <<= 1) ss += __shfl_xor(ss, m);
  __shared__ float wss[4];
  if ((t & 63) == 0) wss[t >> 6] = ss;
  __syncthreads();
  float tot = wss[0] + wss[1] + wss[2] + wss[3];
  float inv = 1.0f / fmaxf(sqrtf(tot), 1e-12f);
  int pk = __builtin_amdgcn_cvt_pk_fp8_f32(v.x * inv, v.y * inv, 0, false);
  pk = __builtin_amdgcn_cvt_pk_fp8_f32(v.z * inv, v.w * inv, pk, true);
  *(unsigned int*)(dst + (size_t)t * 4) = (unsigned int)pk;
}

// -------- Kernel 2: fused fp8 GEMM (16x16x32_fp8_fp8, BK=128B) + exp + masked reductions --------
// Round-9 core with the ct-loop moved into the grid (one 128x128 tile per
// block): no partials persist across the GEMM -> live regs ~110 < 128 cap,
// spill-free without fighting the allocator.
__global__ __launch_bounds__(256, 2)
void gemm_reduce_kernel(const unsigned char* __restrict__ Cn,
                        const unsigned char* __restrict__ Gn,
                        const int* __restrict__ labels,
                        float* __restrict__ ws_sp,
                        float* __restrict__ ws_sa,
                        float* __restrict__ ws_mx) {
  __shared__ __align__(16) unsigned char As[BM * BKB];   // 16 KiB
  __shared__ __align__(16) unsigned char Bs[BN * BKB];   // 16 KiB
  __shared__ float red_sa[2][BM];
  __shared__ float red_sp[2][BM];
  __shared__ float red_mx[2][BM];

  const int tid = threadIdx.x;
  const int lane = tid & 63;
  const int wv = tid >> 6;
  const int wr = wv >> 1, wc = wv & 1;
  const int row0 = blockIdx.x * BM;
  const int chunk = blockIdx.y;
  const int col0 = chunk * BN;
  const int g = lane >> 4;        // k-group 0..3
  const int fr = lane & 15;       // fragment row/col 0..15
  const int fr7 = fr & 7;

  // staging: region r = wv*4+i covers rows r*8..r*8+7 (128 B each).
  // LDS written linearly (base + lane*16B); XOR swizzle pre-applied on the
  // GLOBAL source 16B-slot (slot ^= row&7)  [rule #21; verified rounds 2/9].
  const int srow = lane >> 3;                 // 0..7
  const int scol = (lane & 7) ^ srow;         // pre-swizzled 16B slot (8/row)

  // frag read slot byte-offsets (row&7 == fr&7): slots g and 4+g
  const int sl0 = ((g) ^ fr7) << 4;
  const int sl1 = ((4 + g) ^ fr7) << 4;

  f32x4 acc[4][4];
  #pragma unroll
  for (int m = 0; m < 4; ++m)
    #pragma unroll
    for (int n = 0; n < 4; ++n) {
      f32x4 z = {0.f, 0.f, 0.f, 0.f};
      acc[m][n] = z;
    }

  for (int kt = 0; kt < DIM / BKB; ++kt) {   // 8 iterations
    const int k0 = kt * BKB;
    #pragma unroll
    for (int i = 0; i < 4; ++i) {
      int r = wv * 4 + i;
      gload_lds16(Cn + (size_t)(row0 + r*8 + srow) * DIM + k0 + scol*16, &As[r * 1024]);
    }
    #pragma unroll
    for (int i = 0; i < 4; ++i) {
      int r = wv * 4 + i;
      gload_lds16(Gn + (size_t)(col0 + r*8 + srow) * DIM + k0 + scol*16, &Bs[r * 1024]);
    }
    __syncthreads();
    // half-phase 0: slot g  (32 frag VGPRs live), 32 MFMAs
    {
      i64x2 af[4], bfr[4];
      #pragma unroll
      for (int m = 0; m < 4; ++m)
        af[m] = *(const i64x2*)&As[(wr*64 + m*16 + fr) * BKB + sl0];
      #pragma unroll
      for (int n = 0; n < 4; ++n)
        bfr[n] = *(const i64x2*)&Bs[(wc*64 + n*16 + fr) * BKB + sl0];
      #pragma unroll
      for (int m = 0; m < 4; ++m)
        #pragma unroll
        for (int n = 0; n < 4; ++n) {
          acc[m][n] = __builtin_amdgcn_mfma_f32_16x16x32_fp8_fp8(
              af[m][0], bfr[n][0], acc[m][n], 0, 0, 0);
          acc[m][n] = __builtin_amdgcn_mfma_f32_16x16x32_fp8_fp8(
              af[m][1], bfr[n][1], acc[m][n], 0, 0, 0);
        }
    }
    // half-phase 1: slot 4+g, 32 MFMAs
    {
      i64x2 af[4], bfr[4];
      #pragma unroll
      for (int m = 0; m < 4; ++m)
        af[m] = *(const i64x2*)&As[(wr*64 + m*16 + fr) * BKB + sl1];
      #pragma unroll
      for (int n = 0; n < 4; ++n)
        bfr[n] = *(const i64x2*)&Bs[(wc*64 + n*16 + fr) * BKB + sl1];
      #pragma unroll
      for (int m = 0; m < 4; ++m)
        #pragma unroll
        for (int n = 0; n < 4; ++n) {
          acc[m][n] = __builtin_amdgcn_mfma_f32_16x16x32_fp8_fp8(
              af[m][0], bfr[n][0], acc[m][n], 0, 0, 0);
          acc[m][n] = __builtin_amdgcn_mfma_f32_16x16x32_fp8_fp8(
              af[m][1], bfr[n][1], acc[m][n], 0, 0, 0);
        }
    }
    __syncthreads();
  }

  // epilogue (once per block): exp + masked reduction (verbatim round-9 math)
  int cl[4], cg[4];
  #pragma unroll
  for (int n = 0; n < 4; ++n) {
    cg[n] = col0 + wc*64 + n*16 + fr;
    cl[n] = labels[cg[n]];
  }
  #pragma unroll
  for (int m = 0; m < 4; ++m) {
    #pragma unroll
    for (int j = 0; j < 4; ++j) {
      const int rloc = wr*64 + m*16 + g*4 + j;
      const int rgi = row0 + rloc;
      const int rlab = labels[rgi];
      float va = 0.f, vp = 0.f, vm = NEGINF;
      #pragma unroll
      for (int n = 0; n < 4; ++n) {
        float s10 = acc[m][n][j] * TEMP_INV;
        float e = __expf(s10);
        bool offd = (rgi != cg[n]);
        float ea = offd ? e : 0.f;
        va += ea;
        vp += (rlab == cl[n]) ? ea : 0.f;
        vm = offd ? fmaxf(vm, s10) : vm;
      }
      #pragma unroll
      for (int mk = 1; mk < 16; mk <<= 1) {
        va += __shfl_xor(va, mk);
        vp += __shfl_xor(vp, mk);
        vm = fmaxf(vm, __shfl_xor(vm, mk));
      }
      if (fr == 0) {
        red_sa[wc][rloc] = va;
        red_sp[wc][rloc] = vp;
        red_mx[wc][rloc] = vm;
      }
    }
  }
  __syncthreads();
  if (tid < BM) {
    size_t o = (size_t)chunk * N_ROWS + row0 + tid;
    ws_sa[o] = red_sa[0][tid] + red_sa[1][tid];
    ws_sp[o] = red_sp[0][tid] + red_sp[1][tid];
    ws_mx[o] = fmaxf(red_mx[0][tid], red_mx[1][tid]);
  }
}

// -------- Kernel 3: combine chunk partials -> per-row loss --------
__global__ void finalize_rows_kernel(const float* __restrict__ ws_sp,
                                     const float* __restrict__ ws_sa,
                                     const float* __restrict__ ws_mx,
                                     float* __restrict__ ws_loss) {
  int r = blockIdx.x * blockDim.x + threadIdx.x;
  float sp = 0.f, sa = 0.f, mx = NEGINF;
  #pragma unroll 8
  for (int c = 0; c < NCHUNK; ++c) {
    sp += ws_sp[(size_t)c * N_ROWS + r];
    sa += ws_sa[(size_t)c * N_ROWS + r];
    mx = fmaxf(mx, ws_mx[(size_t)c * N_ROWS + r]);
  }
  float frac = (sp + 1e-8f) / (sa + 1e-8f);
  frac = fminf(fmaxf(frac, 1e-8f), 1.0f);
  float loss = -logf(frac);
  if (sp == 0.0f) loss = -mx;   // no-positives fallback (every exp term > 0)
  ws_loss[r] = loss;
}

// -------- Kernel 4: deterministic mean --------
__global__ void mean_kernel(const float* __restrict__ ws_loss, float* __restrict__ out) {
  int t = threadIdx.x;
  float s = 0.f;
  for (int i = t; i < N_ROWS; i += 256) s += ws_loss[i];
  #pragma unroll
  for (int m = 1; m < 64; m <<= 1) s += __shfl_xor(s, m);
  __shared__ float wsum[4];
  if ((t & 63) == 0) wsum[t >> 6] = s;
  __syncthreads();
  if (t == 0) out[0] = (wsum[0] + wsum[1] + wsum[2] + wsum[3]) * (1.0f / N_ROWS);
}

extern "C" void kernel_launch(void* const* d_in, const int* in_sizes, int n_in,
                              void* d_out, int out_size, void* d_ws, size_t ws_size,
                              hipStream_t stream) {
  const float* ctx = (const float*)d_in[0];
  const float* gls = (const float*)d_in[1];
  const int* labels = (const int*)d_in[2];
  float* out = (float*)d_out;

  char* ws = (char*)d_ws;
  unsigned char* Cn = (unsigned char*)ws;                                 // 8 MiB
  unsigned char* Gn = (unsigned char*)(ws + (size_t)N_ROWS * DIM);        // 8 MiB
  float* ws_sp = (float*)(ws + (size_t)2 * N_ROWS * DIM);
  float* ws_sa = ws_sp + (size_t)NCHUNK * N_ROWS;
  float* ws_mx = ws_sa + (size_t)NCHUNK * N_ROWS;
  float* ws_loss = ws_mx + (size_t)NCHUNK * N_ROWS;

  hipLaunchKernelGGL(norm_fp8_kernel, dim3(2 * N_ROWS), dim3(256), 0, stream,
                     ctx, gls, Cn, Gn);
  hipLaunchKernelGGL(gemm_reduce_kernel, dim3(N_ROWS / BM, NCHUNK), dim3(256), 0, stream,
                     Cn, Gn, labels, ws_sp, ws_sa, ws_mx);
  hipLaunchKernelGGL(finalize_rows_kernel, dim3(N_ROWS / 256), dim3(256), 0, stream,
                     ws_sp, ws_sa, ws_mx, ws_loss);
  hipLaunchKernelGGL(mean_kernel, dim3(1), dim3(256), 0, stream, ws_loss, out);
}

// Round 15
// 136.506 us; speedup vs baseline: 5.8129x; 1.0511x over previous
//
#include <hip/hip_runtime.h>
#include <hip/hip_bf16.h>
#include <stdint.h>

#define N_ROWS 8192
#define DIM    1024            // elements per row; fp8 => also bytes per row
#define TEMP_INV 10.0f
#define NCHUNK 64
#define BM 128
#define BN 128
#define BKB 128                // K-bytes per tile (fp8: 128 elems)
#define NEGINF (-__builtin_inff())

typedef __attribute__((ext_vector_type(2))) long i64x2;
typedef __attribute__((ext_vector_type(4))) float f32x4;

__device__ __forceinline__ void gload_lds16(const void* g, void* l) {
  __builtin_amdgcn_global_load_lds(
      (const __attribute__((address_space(1))) unsigned int*)g,
      (__attribute__((address_space(3))) unsigned int*)l, 16, 0, 0);
}

// -------- Kernel 1: L2-normalize rows -> fp8 e4m3 (1 wave = 1 row; no LDS/barrier) --------
__global__ void norm_fp8_kernel(const float* __restrict__ ctx,
                                const float* __restrict__ gls,
                                unsigned char* __restrict__ Cn,
                                unsigned char* __restrict__ Gn) {
  const int wid = blockIdx.x * 4 + (threadIdx.x >> 6);   // row 0..16383
  const int lane = threadIdx.x & 63;
  const float* src;
  unsigned char* dst;
  if (wid < N_ROWS) { src = ctx + (size_t)wid * DIM; dst = Cn + (size_t)wid * DIM; }
  else { src = gls + (size_t)(wid - N_ROWS) * DIM; dst = Gn + (size_t)(wid - N_ROWS) * DIM; }
  float4 v[4];
  float ss = 0.f;
  #pragma unroll
  for (int q = 0; q < 4; ++q) {
    v[q] = ((const float4*)src)[lane + q * 64];
    ss += v[q].x * v[q].x + v[q].y * v[q].y + v[q].z * v[q].z + v[q].w * v[q].w;
  }
  #pragma unroll
  for (int m = 1; m < 64; m <<= 1) ss += __shfl_xor(ss, m);
  float inv = 1.0f / fmaxf(sqrtf(ss), 1e-12f);
  #pragma unroll
  for (int q = 0; q < 4; ++q) {
    int pk = __builtin_amdgcn_cvt_pk_fp8_f32(v[q].x * inv, v[q].y * inv, 0, false);
    pk = __builtin_amdgcn_cvt_pk_fp8_f32(v[q].z * inv, v[q].w * inv, pk, true);
    *(unsigned int*)(dst + (size_t)(lane + q * 64) * 4) = (unsigned int)pk;
  }
}

// -------- Kernel 2: fused fp8 GEMM (16x16x32_fp8_fp8, BK=128B) + exp + masked reductions --------
// Round-13 structure (VGPR 72, zero spill, 0 conflicts) + T5 setprio around
// the MFMA half-phases (4 independent blocks/CU -> wave role diversity).
__global__ __launch_bounds__(256, 2)
void gemm_reduce_kernel(const unsigned char* __restrict__ Cn,
                        const unsigned char* __restrict__ Gn,
                        const int* __restrict__ labels,
                        float* __restrict__ ws_sp,
                        float* __restrict__ ws_sa,
                        float* __restrict__ ws_mx) {
  __shared__ __align__(16) unsigned char As[BM * BKB];   // 16 KiB
  __shared__ __align__(16) unsigned char Bs[BN * BKB];   // 16 KiB
  __shared__ float red_sa[2][BM];
  __shared__ float red_sp[2][BM];
  __shared__ float red_mx[2][BM];

  const int tid = threadIdx.x;
  const int lane = tid & 63;
  const int wv = tid >> 6;
  const int wr = wv >> 1, wc = wv & 1;
  const int row0 = blockIdx.x * BM;
  const int chunk = blockIdx.y;
  const int col0 = chunk * BN;
  const int g = lane >> 4;        // k-group 0..3
  const int fr = lane & 15;       // fragment row/col 0..15
  const int fr7 = fr & 7;

  // staging: region r = wv*4+i covers rows r*8..r*8+7 (128 B each).
  // LDS written linearly (base + lane*16B); XOR swizzle pre-applied on the
  // GLOBAL source 16B-slot (slot ^= row&7)  [rule #21; verified rounds 2/9/13].
  const int srow = lane >> 3;                 // 0..7
  const int scol = (lane & 7) ^ srow;         // pre-swizzled 16B slot (8/row)

  // frag read slot byte-offsets (row&7 == fr&7): slots g and 4+g
  const int sl0 = ((g) ^ fr7) << 4;
  const int sl1 = ((4 + g) ^ fr7) << 4;

  f32x4 acc[4][4];
  #pragma unroll
  for (int m = 0; m < 4; ++m)
    #pragma unroll
    for (int n = 0; n < 4; ++n) {
      f32x4 z = {0.f, 0.f, 0.f, 0.f};
      acc[m][n] = z;
    }

  for (int kt = 0; kt < DIM / BKB; ++kt) {   // 8 iterations
    const int k0 = kt * BKB;
    #pragma unroll
    for (int i = 0; i < 4; ++i) {
      int r = wv * 4 + i;
      gload_lds16(Cn + (size_t)(row0 + r*8 + srow) * DIM + k0 + scol*16, &As[r * 1024]);
    }
    #pragma unroll
    for (int i = 0; i < 4; ++i) {
      int r = wv * 4 + i;
      gload_lds16(Gn + (size_t)(col0 + r*8 + srow) * DIM + k0 + scol*16, &Bs[r * 1024]);
    }
    __syncthreads();
    // half-phase 0: slot g  (32 frag VGPRs live), 32 MFMAs
    {
      i64x2 af[4], bfr[4];
      #pragma unroll
      for (int m = 0; m < 4; ++m)
        af[m] = *(const i64x2*)&As[(wr*64 + m*16 + fr) * BKB + sl0];
      #pragma unroll
      for (int n = 0; n < 4; ++n)
        bfr[n] = *(const i64x2*)&Bs[(wc*64 + n*16 + fr) * BKB + sl0];
      __builtin_amdgcn_s_setprio(1);
      #pragma unroll
      for (int m = 0; m < 4; ++m)
        #pragma unroll
        for (int n = 0; n < 4; ++n) {
          acc[m][n] = __builtin_amdgcn_mfma_f32_16x16x32_fp8_fp8(
              af[m][0], bfr[n][0], acc[m][n], 0, 0, 0);
          acc[m][n] = __builtin_amdgcn_mfma_f32_16x16x32_fp8_fp8(
              af[m][1], bfr[n][1], acc[m][n], 0, 0, 0);
        }
      __builtin_amdgcn_s_setprio(0);
    }
    // half-phase 1: slot 4+g, 32 MFMAs
    {
      i64x2 af[4], bfr[4];
      #pragma unroll
      for (int m = 0; m < 4; ++m)
        af[m] = *(const i64x2*)&As[(wr*64 + m*16 + fr) * BKB + sl1];
      #pragma unroll
      for (int n = 0; n < 4; ++n)
        bfr[n] = *(const i64x2*)&Bs[(wc*64 + n*16 + fr) * BKB + sl1];
      __builtin_amdgcn_s_setprio(1);
      #pragma unroll
      for (int m = 0; m < 4; ++m)
        #pragma unroll
        for (int n = 0; n < 4; ++n) {
          acc[m][n] = __builtin_amdgcn_mfma_f32_16x16x32_fp8_fp8(
              af[m][0], bfr[n][0], acc[m][n], 0, 0, 0);
          acc[m][n] = __builtin_amdgcn_mfma_f32_16x16x32_fp8_fp8(
              af[m][1], bfr[n][1], acc[m][n], 0, 0, 0);
        }
      __builtin_amdgcn_s_setprio(0);
    }
    __syncthreads();
  }

  // epilogue (once per block): exp + masked reduction (verbatim round-9 math)
  int cl[4], cg[4];
  #pragma unroll
  for (int n = 0; n < 4; ++n) {
    cg[n] = col0 + wc*64 + n*16 + fr;
    cl[n] = labels[cg[n]];
  }
  #pragma unroll
  for (int m = 0; m < 4; ++m) {
    #pragma unroll
    for (int j = 0; j < 4; ++j) {
      const int rloc = wr*64 + m*16 + g*4 + j;
      const int rgi = row0 + rloc;
      const int rlab = labels[rgi];
      float va = 0.f, vp = 0.f, vm = NEGINF;
      #pragma unroll
      for (int n = 0; n < 4; ++n) {
        float s10 = acc[m][n][j] * TEMP_INV;
        float e = __expf(s10);
        bool offd = (rgi != cg[n]);
        float ea = offd ? e : 0.f;
        va += ea;
        vp += (rlab == cl[n]) ? ea : 0.f;
        vm = offd ? fmaxf(vm, s10) : vm;
      }
      #pragma unroll
      for (int mk = 1; mk < 16; mk <<= 1) {
        va += __shfl_xor(va, mk);
        vp += __shfl_xor(vp, mk);
        vm = fmaxf(vm, __shfl_xor(vm, mk));
      }
      if (fr == 0) {
        red_sa[wc][rloc] = va;
        red_sp[wc][rloc] = vp;
        red_mx[wc][rloc] = vm;
      }
    }
  }
  __syncthreads();
  if (tid < BM) {
    size_t o = (size_t)chunk * N_ROWS + row0 + tid;
    ws_sa[o] = red_sa[0][tid] + red_sa[1][tid];
    ws_sp[o] = red_sp[0][tid] + red_sp[1][tid];
    ws_mx[o] = fmaxf(red_mx[0][tid], red_mx[1][tid]);
  }
}

// -------- Kernel 3: combine chunk partials -> per-row loss -> 32 block partials --------
__global__ void finalize_rows_kernel(const float* __restrict__ ws_sp,
                                     const float* __restrict__ ws_sa,
                                     const float* __restrict__ ws_mx,
                                     float* __restrict__ ws_part) {
  int r = blockIdx.x * blockDim.x + threadIdx.x;
  float sp = 0.f, sa = 0.f, mx = NEGINF;
  #pragma unroll 8
  for (int c = 0; c < NCHUNK; ++c) {
    sp += ws_sp[(size_t)c * N_ROWS + r];
    sa += ws_sa[(size_t)c * N_ROWS + r];
    mx = fmaxf(mx, ws_mx[(size_t)c * N_ROWS + r]);
  }
  float frac = (sp + 1e-8f) / (sa + 1e-8f);
  frac = fminf(fmaxf(frac, 1e-8f), 1.0f);
  float loss = -logf(frac);
  if (sp == 0.0f) loss = -mx;   // no-positives fallback (every exp term > 0)
  // deterministic in-block reduction
  int t = threadIdx.x;
  #pragma unroll
  for (int m = 1; m < 64; m <<= 1) loss += __shfl_xor(loss, m);
  __shared__ float wsum[4];
  if ((t & 63) == 0) wsum[t >> 6] = loss;
  __syncthreads();
  if (t == 0) ws_part[blockIdx.x] = (wsum[0] + wsum[1]) + (wsum[2] + wsum[3]);
}

// -------- Kernel 4: deterministic mean over 32 block partials --------
__global__ void mean_kernel(const float* __restrict__ ws_part, float* __restrict__ out) {
  int t = threadIdx.x;                       // 64 threads
  float s = (t < N_ROWS / 256) ? ws_part[t] : 0.f;
  #pragma unroll
  for (int m = 1; m < 64; m <<= 1) s += __shfl_xor(s, m);
  if (t == 0) out[0] = s * (1.0f / N_ROWS);
}

extern "C" void kernel_launch(void* const* d_in, const int* in_sizes, int n_in,
                              void* d_out, int out_size, void* d_ws, size_t ws_size,
                              hipStream_t stream) {
  const float* ctx = (const float*)d_in[0];
  const float* gls = (const float*)d_in[1];
  const int* labels = (const int*)d_in[2];
  float* out = (float*)d_out;

  char* ws = (char*)d_ws;
  unsigned char* Cn = (unsigned char*)ws;                                 // 8 MiB
  unsigned char* Gn = (unsigned char*)(ws + (size_t)N_ROWS * DIM);        // 8 MiB
  float* ws_sp = (float*)(ws + (size_t)2 * N_ROWS * DIM);
  float* ws_sa = ws_sp + (size_t)NCHUNK * N_ROWS;
  float* ws_mx = ws_sa + (size_t)NCHUNK * N_ROWS;
  float* ws_part = ws_mx + (size_t)NCHUNK * N_ROWS;

  hipLaunchKernelGGL(norm_fp8_kernel, dim3(4096), dim3(256), 0, stream,
                     ctx, gls, Cn, Gn);
  hipLaunchKernelGGL(gemm_reduce_kernel, dim3(N_ROWS / BM, NCHUNK), dim3(256), 0, stream,
                     Cn, Gn, labels, ws_sp, ws_sa, ws_mx);
  hipLaunchKernelGGL(finalize_rows_kernel, dim3(N_ROWS / 256), dim3(256), 0, stream,
                     ws_sp, ws_sa, ws_mx, ws_part);
  hipLaunchKernelGGL(mean_kernel, dim3(1), dim3(64), 0, stream, ws_part, out);
}